// Round 6
// baseline (334.881 us; speedup 1.0000x reference)
//
#include <hip/hip_runtime.h>

// GAE backward scan: B=8192 rows, S=2048 steps, fp32.
// R5b: row-granularity software pipeline (R5 + fix: nontemporal stores need
// native clang ext_vector_type, not HIP_vector_type float4).
// One workgroup (4 waves) handles 4 rows; loads for row r+1 issued before
// the scan/apply/store phase of row r -> ~8KB/wave in flight through the
// DS-latency-bound scan phase. Outputs stored nontemporally (write-once).

static constexpr int BATCH = 8192;
static constexpr int SEQ   = 2048;
static constexpr int EPL   = 8;     // elements per lane
static constexpr int ROWS  = 4;     // rows per workgroup (pipeline depth)
static constexpr float GAMMA  = 0.999f;
static constexpr float LAMBDA = 0.95f;
static constexpr float GL     = GAMMA * LAMBDA;

typedef float fx4 __attribute__((ext_vector_type(4)));
typedef int   ix4 __attribute__((ext_vector_type(4)));

struct Raw {
    fx4 r0, r1, v0, v1;
    ix4 d0, d1, m0, m1;
};

__device__ __forceinline__ Raw load_row(const float* __restrict__ R,
                                        const float* __restrict__ V,
                                        const int*   __restrict__ D,
                                        const int*   __restrict__ M,
                                        size_t off) {
    Raw x;
    x.r0 = *reinterpret_cast<const fx4*>(R + off);
    x.r1 = *reinterpret_cast<const fx4*>(R + off + 4);
    x.v0 = *reinterpret_cast<const fx4*>(V + off);
    x.v1 = *reinterpret_cast<const fx4*>(V + off + 4);
    x.d0 = *reinterpret_cast<const ix4*>(D + off);
    x.d1 = *reinterpret_cast<const ix4*>(D + off + 4);
    x.m0 = *reinterpret_cast<const ix4*>(M + off);
    x.m1 = *reinterpret_cast<const ix4*>(M + off + 4);
    return x;
}

__global__ __launch_bounds__(256, 4) void gae_kernel(
    const float* __restrict__ rewards,
    const float* __restrict__ values,
    const int*   __restrict__ dones,
    const int*   __restrict__ mask,
    float*       __restrict__ out)   // [2*B*S]: advantages then returns
{
    __shared__ float sF[2][4], sA[2][4], sB[2][4];  // double-buffered per parity

    const int lane = threadIdx.x & 63;
    const int wave = threadIdx.x >> 6;
    const int row0 = blockIdx.x * ROWS;
    const size_t tof = (size_t)threadIdx.x * EPL;

    Raw cur = load_row(rewards, values, dones, mask, (size_t)row0 * SEQ + tof);

    #pragma unroll
    for (int r = 0; r < ROWS; ++r) {
        const int p = r & 1;
        const size_t off = (size_t)(row0 + r) * SEQ + tof;

        const float rr[EPL] = {cur.r0.x, cur.r0.y, cur.r0.z, cur.r0.w,
                               cur.r1.x, cur.r1.y, cur.r1.z, cur.r1.w};
        const float vv[EPL] = {cur.v0.x, cur.v0.y, cur.v0.z, cur.v0.w,
                               cur.v1.x, cur.v1.y, cur.v1.z, cur.v1.w};
        const int   dd[EPL] = {cur.d0.x, cur.d0.y, cur.d0.z, cur.d0.w,
                               cur.d1.x, cur.d1.y, cur.d1.z, cur.d1.w};
        const int   mm[EPL] = {cur.m0.x, cur.m0.y, cur.m0.z, cur.m0.w,
                               cur.m1.x, cur.m1.y, cur.m1.z, cur.m1.w};

        float a[EPL], b[EPL], vm[EPL];
        #pragma unroll
        for (int e = 0; e < EPL; ++e) {
            const bool m  = (mm[e] != 0);
            const bool mn = m && (dd[e] == 0);
            vm[e] = m ? vv[e] : 0.0f;
            a[e]  = mn ? GL : 0.0f;
        }

        if (lane == 0) sF[p][wave] = vm[0];
        __syncthreads();
        float nv7 = __shfl_down(vm[0], 1, 64);
        if (lane == 63) nv7 = (wave < 3) ? sF[p][wave + 1] : 0.0f;

        #pragma unroll
        for (int e = 0; e < EPL; ++e) {
            const bool  m   = (mm[e] != 0);
            const bool  mn  = m && (dd[e] == 0);
            const float mr  = m ? rr[e] : 0.0f;
            const float mnd = mn ? 1.0f : 0.0f;
            const float nv  = (e < EPL - 1) ? vm[e + 1] : nv7;
            b[e] = mr + GAMMA * nv * mnd - vm[e];
        }

        // Prefetch next row's raw data: in flight through the scan below.
        Raw nxt;
        if (r + 1 < ROWS)
            nxt = load_row(rewards, values, dones, mask, off + SEQ);

        // Local reverse-time affine composition over this lane's 8 steps.
        float A = a[EPL - 1], B = b[EPL - 1];
        #pragma unroll
        for (int e = EPL - 2; e >= 0; --e) {
            B = fmaf(a[e], B, b[e]);
            A = a[e] * A;
        }

        // Wave inclusive suffix scan (lane l -> composition over lanes [l,63]).
        float As = A, Bs = B;
        #pragma unroll
        for (int d = 1; d < 64; d <<= 1) {
            const float Ao = __shfl_down(As, d, 64);
            const float Bo = __shfl_down(Bs, d, 64);
            if (lane + d < 64) {
                Bs = fmaf(As, Bo, Bs);
                As = As * Ao;
            }
        }

        if (lane == 0) { sA[p][wave] = As; sB[p][wave] = Bs; }
        __syncthreads();
        float C = 0.0f;
        for (int w2 = 3; w2 > wave; --w2)      // wave-uniform, <=3 iterations
            C = fmaf(sA[p][w2], C, sB[p][w2]);

        float cA = __shfl_down(As, 1, 64);
        float cB = __shfl_down(Bs, 1, 64);
        if (lane == 63) { cA = 1.0f; cB = 0.0f; }
        float g = fmaf(cA, C, cB);

        float adv[EPL], ret[EPL];
        #pragma unroll
        for (int e = EPL - 1; e >= 0; --e) {
            g = fmaf(a[e], g, b[e]);
            adv[e] = g;
            ret[e] = g + vm[e];
        }

        fx4 a0 = {adv[0], adv[1], adv[2], adv[3]};
        fx4 a1 = {adv[4], adv[5], adv[6], adv[7]};
        fx4 t0 = {ret[0], ret[1], ret[2], ret[3]};
        fx4 t1 = {ret[4], ret[5], ret[6], ret[7]};
        __builtin_nontemporal_store(a0, reinterpret_cast<fx4*>(out + off));
        __builtin_nontemporal_store(a1, reinterpret_cast<fx4*>(out + off + 4));
        __builtin_nontemporal_store(t0, reinterpret_cast<fx4*>(out + (size_t)BATCH * SEQ + off));
        __builtin_nontemporal_store(t1, reinterpret_cast<fx4*>(out + (size_t)BATCH * SEQ + off + 4));

        if (r + 1 < ROWS) cur = nxt;
    }
}

extern "C" void kernel_launch(void* const* d_in, const int* in_sizes, int n_in,
                              void* d_out, int out_size, void* d_ws, size_t ws_size,
                              hipStream_t stream) {
    const float* rewards = (const float*)d_in[0];
    const float* values  = (const float*)d_in[1];
    const int*   dones   = (const int*)d_in[2];
    const int*   mask    = (const int*)d_in[3];
    float* out = (float*)d_out;

    dim3 grid(BATCH / ROWS), block(256);   // 4 waves/block, 4 rows per block
    gae_kernel<<<grid, block, 0, stream>>>(rewards, values, dones, mask, out);
}